// Round 1
// baseline (1718.582 us; speedup 1.0000x reference)
//
#include <hip/hip_runtime.h>
#include <math.h>

// Problem constants (B,T,C,H fixed by the reference).
#define B_ 2
#define T_ 2048
#define C_ 1024
#define H_ 16
#define HD_ 64
#define M_ (B_*T_)   // 4096 rows for all projection GEMMs

// ---------------------------------------------------------------------------
// GEMM: Out[M,N] = A[M,K] @ W[K,N] + bias[N]   (all fp32)
// BM=BN=128, BK=16, 256 threads, 8x8 micro-tile per thread.
// LDS layout [k][m]/[k][n] with +4 padding -> float4 reads stay 16B aligned,
// worst LDS conflict is 2-way (free on gfx950, m136).
// ---------------------------------------------------------------------------
__global__ __launch_bounds__(256) void gemm_bias_kernel(
    const float* __restrict__ A, const float* __restrict__ W,
    const float* __restrict__ bias, float* __restrict__ Out,
    int Mdim, int Ndim, int Kdim)
{
  __shared__ __align__(16) float As[16][132];  // [k][m], pad 128->132
  __shared__ __align__(16) float Bs[16][132];  // [k][n]
  const int t  = threadIdx.x;
  const int tx = t & 15;   // col group: cols tx*8 .. tx*8+7
  const int ty = t >> 4;   // row group: rows ty*8 .. ty*8+7
  const int bm = blockIdx.y * 128;
  const int bn = blockIdx.x * 128;

  float c[8][8];
#pragma unroll
  for (int i = 0; i < 8; i++)
#pragma unroll
    for (int j = 0; j < 8; j++) c[i][j] = 0.f;

  for (int k0 = 0; k0 < Kdim; k0 += 16) {
    // A tile: 128x16 floats = 512 float4, 2 per thread. Coalesced 16B/lane.
#pragma unroll
    for (int i = 0; i < 2; i++) {
      int e4 = t + i * 256;          // 0..511
      int m  = e4 >> 2;              // 0..127
      int k4 = e4 & 3;               // which float4 within the 16-wide k row
      float4 av = *(const float4*)(A + (size_t)(bm + m) * Kdim + k0 + k4 * 4);
      As[k4 * 4 + 0][m] = av.x;      // transpose to [k][m]; 2-way bank max
      As[k4 * 4 + 1][m] = av.y;
      As[k4 * 4 + 2][m] = av.z;
      As[k4 * 4 + 3][m] = av.w;
    }
    // B tile: 16x128 floats = 512 float4, 2 per thread. Fully coalesced.
#pragma unroll
    for (int i = 0; i < 2; i++) {
      int e4 = t + i * 256;          // 0..511
      int kk = e4 >> 5;              // 0..15
      int n4 = e4 & 31;              // 0..31
      *(float4*)&Bs[kk][n4 * 4] =
          *(const float4*)(W + (size_t)(k0 + kk) * Ndim + bn + n4 * 4);
    }
    __syncthreads();
#pragma unroll
    for (int k = 0; k < 16; k++) {
      float4 a0 = *(const float4*)&As[k][ty * 8];      // broadcast across 16 lanes
      float4 a1 = *(const float4*)&As[k][ty * 8 + 4];
      float4 b0 = *(const float4*)&Bs[k][tx * 8];
      float4 b1 = *(const float4*)&Bs[k][tx * 8 + 4];
      float ar[8] = {a0.x, a0.y, a0.z, a0.w, a1.x, a1.y, a1.z, a1.w};
      float br[8] = {b0.x, b0.y, b0.z, b0.w, b1.x, b1.y, b1.z, b1.w};
#pragma unroll
      for (int i = 0; i < 8; i++)
#pragma unroll
        for (int j = 0; j < 8; j++) c[i][j] = fmaf(ar[i], br[j], c[i][j]);
    }
    __syncthreads();
  }

  float4 bv0 = *(const float4*)(bias + bn + tx * 8);
  float4 bv1 = *(const float4*)(bias + bn + tx * 8 + 4);
  float br[8] = {bv0.x, bv0.y, bv0.z, bv0.w, bv1.x, bv1.y, bv1.z, bv1.w};
#pragma unroll
  for (int i = 0; i < 8; i++) {
    float4 o0, o1;
    o0.x = c[i][0] + br[0]; o0.y = c[i][1] + br[1];
    o0.z = c[i][2] + br[2]; o0.w = c[i][3] + br[3];
    o1.x = c[i][4] + br[4]; o1.y = c[i][5] + br[5];
    o1.z = c[i][6] + br[6]; o1.w = c[i][7] + br[7];
    float* row = Out + (size_t)(bm + ty * 8 + i) * Ndim + bn + tx * 8;
    *(float4*)row       = o0;
    *(float4*)(row + 4) = o1;
  }
}

// ---------------------------------------------------------------------------
// Flash-style attention, fp32, no mask (reference has none).
// Grid: (T/64, H, B). Block: 256 threads = 64 query rows x 4 lanes/row.
// Each lane owns 16 keys of every 64-key tile; online softmax state (m,l)
// replicated across the 4 lanes of a row via __shfl_xor; O accumulator (64
// dims) partial per lane over its key subset, reduced across lanes at the end.
// ---------------------------------------------------------------------------
__global__ __launch_bounds__(256) void attn_kernel(
    const float* __restrict__ Q, const float* __restrict__ Kg,
    const float* __restrict__ V, float* __restrict__ Y)
{
  __shared__ __align__(16) float Ks[64][68];  // [key][dim], pad 64->68
  __shared__ __align__(16) float Vs[64][68];
  const int t  = threadIdx.x;
  const int r  = t >> 2;       // query row within tile: 0..63
  const int q4 = t & 3;        // which quarter of the 64 keys this lane owns
  const int qt = blockIdx.x;   // query tile 0..31
  const int h  = blockIdx.y;   // head
  const int b  = blockIdx.z;   // batch
  const int tq = qt * 64 + r;  // global query index
  const size_t qbase = ((size_t)(b * T_ + tq)) * C_ + h * HD_;

  // Q row (64 floats) in registers, pre-scaled by 1/sqrt(HD)=0.125.
  float4 qreg[16];
#pragma unroll
  for (int i = 0; i < 16; i++) {
    float4 qv = *(const float4*)(Q + qbase + i * 4);
    qv.x *= 0.125f; qv.y *= 0.125f; qv.z *= 0.125f; qv.w *= 0.125f;
    qreg[i] = qv;
  }

  float4 acc[16];
#pragma unroll
  for (int i = 0; i < 16; i++) acc[i] = make_float4(0.f, 0.f, 0.f, 0.f);
  float mrow = -1e30f;  // running row max (replicated across the 4 lanes)
  float lsum = 0.f;     // partial softmax denominator (this lane's keys only)

  for (int kt = 0; kt < 32; kt++) {
    // Stage K,V 64x64 tiles. 1024 float4 each, 4 per thread, coalesced.
#pragma unroll
    for (int i = 0; i < 4; i++) {
      int e  = t + i * 256;      // 0..1023
      int j  = e >> 4;           // key row 0..63
      int d4 = e & 15;           // float4 within row
      size_t g = ((size_t)(b * T_ + kt * 64 + j)) * C_ + h * HD_ + d4 * 4;
      *(float4*)&Ks[j][d4 * 4] = *(const float4*)(Kg + g);
      *(float4*)&Vs[j][d4 * 4] = *(const float4*)(V + g);
    }
    __syncthreads();

    // Scores for this lane's 16 keys (staggered j to spread LDS banks).
    float s[16];
    float tmax = -1e30f;
#pragma unroll
    for (int jj = 0; jj < 16; jj++) {
      int j = (q4 << 4) | ((jj + q4) & 15);
      const float4* krow = (const float4*)&Ks[j][0];
      float sv = 0.f;
#pragma unroll
      for (int i = 0; i < 16; i++) {
        float4 kv = krow[i];
        sv = fmaf(qreg[i].x, kv.x, sv);
        sv = fmaf(qreg[i].y, kv.y, sv);
        sv = fmaf(qreg[i].z, kv.z, sv);
        sv = fmaf(qreg[i].w, kv.w, sv);
      }
      s[jj] = sv;
      tmax  = fmaxf(tmax, sv);
    }
    // Row max across the 4 lanes of this row (lanes 4r..4r+3, same wave).
    tmax = fmaxf(tmax, __shfl_xor(tmax, 1));
    tmax = fmaxf(tmax, __shfl_xor(tmax, 2));
    float mnew  = fmaxf(mrow, tmax);
    float alpha = __expf(mrow - mnew);   // 0 on first tile (mrow=-1e30)
    lsum *= alpha;
#pragma unroll
    for (int i = 0; i < 16; i++) {
      acc[i].x *= alpha; acc[i].y *= alpha; acc[i].z *= alpha; acc[i].w *= alpha;
    }
    float p[16];
    float ps = 0.f;
#pragma unroll
    for (int jj = 0; jj < 16; jj++) {
      p[jj] = __expf(s[jj] - mnew);
      ps += p[jj];
    }
    lsum += ps;
    mrow = mnew;

    // O += P @ V over this lane's 16 keys.
#pragma unroll
    for (int jj = 0; jj < 16; jj++) {
      int j = (q4 << 4) | ((jj + q4) & 15);
      float pj = p[jj];
      const float4* vrow = (const float4*)&Vs[j][0];
#pragma unroll
      for (int i = 0; i < 16; i++) {
        float4 vv = vrow[i];
        acc[i].x = fmaf(pj, vv.x, acc[i].x);
        acc[i].y = fmaf(pj, vv.y, acc[i].y);
        acc[i].z = fmaf(pj, vv.z, acc[i].z);
        acc[i].w = fmaf(pj, vv.w, acc[i].w);
      }
    }
    __syncthreads();  // before next tile overwrites Ks/Vs
  }

  // Reduce partial l and O across the 4 lanes of each row.
  lsum += __shfl_xor(lsum, 1);
  lsum += __shfl_xor(lsum, 2);
#pragma unroll
  for (int i = 0; i < 16; i++) {
    acc[i].x += __shfl_xor(acc[i].x, 1); acc[i].x += __shfl_xor(acc[i].x, 2);
    acc[i].y += __shfl_xor(acc[i].y, 1); acc[i].y += __shfl_xor(acc[i].y, 2);
    acc[i].z += __shfl_xor(acc[i].z, 1); acc[i].z += __shfl_xor(acc[i].z, 2);
    acc[i].w += __shfl_xor(acc[i].w, 1); acc[i].w += __shfl_xor(acc[i].w, 2);
  }
  float inv = 1.0f / lsum;
  // Lane q4 writes dims [16*q4, 16*q4+16). Layout (B,T,C) so the output
  // projection GEMM consumes it directly.
  size_t obase = ((size_t)(b * T_ + tq)) * C_ + h * HD_ + q4 * 16;
#pragma unroll
  for (int ii = 0; ii < 4; ii++) {
    float4 o = acc[q4 * 4 + ii];
    o.x *= inv; o.y *= inv; o.z *= inv; o.w *= inv;
    *(float4*)(Y + obase + ii * 4) = o;
  }
}

// ---------------------------------------------------------------------------
extern "C" void kernel_launch(void* const* d_in, const int* in_sizes, int n_in,
                              void* d_out, int out_size, void* d_ws, size_t ws_size,
                              hipStream_t stream) {
  const float* x  = (const float*)d_in[0];
  const float* Wq = (const float*)d_in[1];
  const float* bq = (const float*)d_in[2];
  const float* Wk = (const float*)d_in[3];
  const float* bk = (const float*)d_in[4];
  const float* Wv = (const float*)d_in[5];
  const float* bv = (const float*)d_in[6];
  const float* Wo = (const float*)d_in[7];
  const float* bo = (const float*)d_in[8];
  float* out = (float*)d_out;

  // Workspace: Q,K,V,Y each M_*C_ fp32 = 16 MB -> 64 MB total.
  const size_t stride = (size_t)M_ * C_;
  float* Qb = (float*)d_ws;
  float* Kb = Qb + stride;
  float* Vb = Kb + stride;
  float* Yb = Vb + stride;

  dim3 gemm_grid(C_ / 128, M_ / 128);  // (8, 32)
  gemm_bias_kernel<<<gemm_grid, 256, 0, stream>>>(x,  Wq, bq, Qb, M_, C_, C_);
  gemm_bias_kernel<<<gemm_grid, 256, 0, stream>>>(x,  Wk, bk, Kb, M_, C_, C_);
  gemm_bias_kernel<<<gemm_grid, 256, 0, stream>>>(x,  Wv, bv, Vb, M_, C_, C_);

  dim3 attn_grid(T_ / 64, H_, B_);     // (32, 16, 2)
  attn_kernel<<<attn_grid, 256, 0, stream>>>(Qb, Kb, Vb, Yb);

  gemm_bias_kernel<<<gemm_grid, 256, 0, stream>>>(Yb, Wo, bo, out, M_, C_, C_);
}

// Round 3
// 236.461 us; speedup vs baseline: 7.2679x; 7.2679x over previous
//
#include <hip/hip_runtime.h>
#include <math.h>

#define B_ 2
#define T_ 2048
#define C_ 1024
#define H_ 16
#define HD_ 64
#define M_ (B_*T_)

typedef _Float16 half4v __attribute__((ext_vector_type(4)));
typedef _Float16 half8v __attribute__((ext_vector_type(8)));
typedef float f32x4 __attribute__((ext_vector_type(4)));

// ---------------------------------------------------------------------------
// Elementwise fp32 -> f16 cast, float4-vectorized.
// ---------------------------------------------------------------------------
__global__ __launch_bounds__(256) void cast_f16_kernel(
    const float* __restrict__ src, _Float16* __restrict__ dst, int n4)
{
  int i = blockIdx.x * 256 + threadIdx.x;
  if (i < n4) {
    float4 v = ((const float4*)src)[i];
    half4v h; h[0] = (_Float16)v.x; h[1] = (_Float16)v.y;
    h[2] = (_Float16)v.z; h[3] = (_Float16)v.w;
    ((half4v*)dst)[i] = h;
  }
}

// ---------------------------------------------------------------------------
// W[K=1024][N=1024] fp32 -> Wt[n][k] f16. 32x32 LDS tiles, block (32,8).
// ---------------------------------------------------------------------------
__global__ __launch_bounds__(256) void transpose_cast_kernel(
    const float* __restrict__ W, _Float16* __restrict__ Wt)
{
  __shared__ float tile[32][33];
  const int tx = threadIdx.x, ty = threadIdx.y;
  const int n0 = blockIdx.x * 32, k0 = blockIdx.y * 32;
#pragma unroll
  for (int r = 0; r < 4; r++) {
    int k = ty + r * 8;
    tile[k][tx] = W[(size_t)(k0 + k) * C_ + n0 + tx];
  }
  __syncthreads();
#pragma unroll
  for (int r = 0; r < 4; r++) {
    int n = ty + r * 8;
    Wt[(size_t)(n0 + n) * C_ + k0 + tx] = (_Float16)tile[tx][n];
  }
}

__global__ __launch_bounds__(256) void concat_bias_kernel(
    const float* __restrict__ bq, const float* __restrict__ bk,
    const float* __restrict__ bv, float* __restrict__ b3)
{
  int i = blockIdx.x * 256 + threadIdx.x;  // grid 12*256 = 3072
  const float* s = (i < 1024) ? bq : ((i < 2048) ? bk : bv);
  b3[i] = s[i & 1023];
}

// ---------------------------------------------------------------------------
// f16 MFMA GEMM: Out[M,N] = A[M,1024] @ Wt[N,1024]^T + bias.
// BK=32, 256 threads = 4 waves in 2x2; wave tile (BM/2)x(BN/2).
// LDS rows = 32 f16 = 4 x 16B chunks, XOR-swizzled: chunk' = chunk ^ ((row>>1)&3)
// -> MFMA fragment reads are 2-way max (free).
// EPI 0: fused QKV epilogue (Q scaled 0.125 -> o0; K -> o1; V transposed -> o2
//        as [b,h,d,t] f16).  EPI 1: fp32 out + bias (of).
// ---------------------------------------------------------------------------
template <int BM, int BN, int EPI>
__global__ __launch_bounds__(256) void gemm_f16_kernel(
    const _Float16* __restrict__ A, const _Float16* __restrict__ Bw,
    const float* __restrict__ bias,
    _Float16* __restrict__ o0, _Float16* __restrict__ o1,
    _Float16* __restrict__ o2, float* __restrict__ of)
{
  constexpr int FM = BM / 32, FN = BN / 32;
  __shared__ __align__(16) _Float16 smem[(BM + BN) * 32];
  _Float16* As = smem;
  _Float16* Bs = smem + BM * 32;
  const int t = threadIdx.x;
  const int w = t >> 6, lane = t & 63, l15 = lane & 15, quad = lane >> 4;
  const int wm = (w & 1) * (BM / 2), wn = (w >> 1) * (BN / 2);
  const int bm = blockIdx.y * BM, bn = blockIdx.x * BN;

  f32x4 acc[FM][FN];
#pragma unroll
  for (int i = 0; i < FM; i++)
#pragma unroll
    for (int j = 0; j < FN; j++) acc[i][j] = (f32x4){0.f, 0.f, 0.f, 0.f};

  for (int k0 = 0; k0 < 1024; k0 += 32) {
    // Stage A tile (BM x 32), swizzled 16B chunks.
#pragma unroll
    for (int i = 0; i < BM * 4 / 256; i++) {
      int slot = t + i * 256;
      int row = slot >> 2, cp = slot & 3;
      int c = cp ^ ((row >> 1) & 3);
      *(uint4*)((char*)As + slot * 16) =
          *(const uint4*)(A + (size_t)(bm + row) * 1024 + k0 + c * 8);
    }
    // Stage B tile (BN x 32).
#pragma unroll
    for (int i = 0; i < BN * 4 / 256; i++) {
      int slot = t + i * 256;
      int row = slot >> 2, cp = slot & 3;
      int c = cp ^ ((row >> 1) & 3);
      *(uint4*)((char*)Bs + slot * 16) =
          *(const uint4*)(Bw + (size_t)(bn + row) * 1024 + k0 + c * 8);
    }
    __syncthreads();

    half8v af[FM], bf[FN];
#pragma unroll
    for (int mt = 0; mt < FM; mt++) {
      int row = wm + mt * 16 + l15;
      int ch = quad ^ ((row >> 1) & 3);
      af[mt] = *(const half8v*)((char*)As + row * 64 + ch * 16);
    }
#pragma unroll
    for (int nt = 0; nt < FN; nt++) {
      int row = wn + nt * 16 + l15;
      int ch = quad ^ ((row >> 1) & 3);
      bf[nt] = *(const half8v*)((char*)Bs + row * 64 + ch * 16);
    }
#pragma unroll
    for (int mt = 0; mt < FM; mt++)
#pragma unroll
      for (int nt = 0; nt < FN; nt++)
        acc[mt][nt] = __builtin_amdgcn_mfma_f32_16x16x32_f16(
            af[mt], bf[nt], acc[mt][nt], 0, 0, 0);
    __syncthreads();
  }

  // Epilogue. C/D layout: col = l15 (n), row = quad*4 + r (m).
#pragma unroll
  for (int mt = 0; mt < FM; mt++)
#pragma unroll
    for (int nt = 0; nt < FN; nt++) {
      int n = bn + wn + nt * 16 + l15;
      float bv = bias[n];
#pragma unroll
      for (int r = 0; r < 4; r++) {
        int m = bm + wm + mt * 16 + quad * 4 + r;
        float v = acc[mt][nt][r] + bv;
        if (EPI == 0) {
          if (bn < 1024) {
            o0[(size_t)m * 1024 + n] = (_Float16)(v * 0.125f);  // Q pre-scaled
          } else if (bn < 2048) {
            o1[(size_t)m * 1024 + (n - 1024)] = (_Float16)v;    // K
          } else {
            int dg = n - 2048;
            int hh = dg >> 6, hd = dg & 63;
            int bb = m >> 11, tt = m & 2047;
            o2[(((size_t)(bb * H_ + hh)) * 64 + hd) * 2048 + tt] = (_Float16)v;  // V^T
          }
        } else {
          of[(size_t)m * 1024 + n] = v;
        }
      }
    }
}

// ---------------------------------------------------------------------------
// MFMA flash attention (no mask, per reference). Grid (T/64, H, B), 256 thr.
// Wave w owns 16 query columns q = qt*64 + w*16 + l15.
// S^T = K·Q^T via 16x16x32_f16  (C-layout: row=key=quad*4+reg, col=q=l15).
// Softmax state per lane (its q column), reduced across quads via shfl 16/32.
// P lands exactly in the 16x16x16f16 B-operand layout (k=quad*4+j), so
// PV: o^T[d][q] += V^T-frag (A) x P (B) with zero LDS round-trip.
// K tile LDS [key][d] and V tile LDS [d][key], 16B-chunk XOR swizzle (^row&7)
// -> fragment reads 2-way max.
// ---------------------------------------------------------------------------
__global__ __launch_bounds__(256) void attn_f16_kernel(
    const _Float16* __restrict__ Qh, const _Float16* __restrict__ Kh,
    const _Float16* __restrict__ Vt, _Float16* __restrict__ Yh)
{
  __shared__ __align__(16) _Float16 Ks[64 * 64];
  __shared__ __align__(16) _Float16 Vs[64 * 64];
  const int t = threadIdx.x;
  const int w = t >> 6, lane = t & 63, l15 = lane & 15, quad = lane >> 4;
  const int qt = blockIdx.x, h = blockIdx.y, b = blockIdx.z;
  const int qg = qt * 64 + w * 16 + l15;
  const size_t qoff = ((size_t)(b * T_ + qg)) * C_ + h * HD_;

  half8v qf[2];
  qf[0] = *(const half8v*)(Qh + qoff + quad * 8);
  qf[1] = *(const half8v*)(Qh + qoff + 32 + quad * 8);

  f32x4 o[4];
#pragma unroll
  for (int i = 0; i < 4; i++) o[i] = (f32x4){0.f, 0.f, 0.f, 0.f};
  float m_run = -INFINITY, l_run = 0.f;

  const size_t kbase = ((size_t)b * T_) * C_ + h * HD_;
  const size_t vbase = ((size_t)(b * H_ + h)) * HD_ * 2048;

  for (int kt0 = 0; kt0 < T_; kt0 += 64) {
    // Stage K (64 keys x 64 d) and V^T (64 d x 64 keys); 512 slots each.
#pragma unroll
    for (int i = 0; i < 2; i++) {
      int slot = t + i * 256;
      int row = slot >> 3, cp = slot & 7;
      int c = cp ^ (row & 7);
      *(uint4*)((char*)Ks + slot * 16) =
          *(const uint4*)(Kh + kbase + (size_t)(kt0 + row) * C_ + c * 8);
      *(uint4*)((char*)Vs + slot * 16) =
          *(const uint4*)(Vt + vbase + (size_t)row * 2048 + kt0 + c * 8);
    }
    __syncthreads();

    // S^T tiles: 4 key-tiles x 2 d-steps.
    f32x4 s[4];
#pragma unroll
    for (int kt = 0; kt < 4; kt++) {
      s[kt] = (f32x4){0.f, 0.f, 0.f, 0.f};
      int key = kt * 16 + l15;
#pragma unroll
      for (int ks = 0; ks < 2; ks++) {
        half8v kf = *(const half8v*)(
            (char*)Ks + key * 128 + (((ks * 4 + quad) ^ (key & 7)) * 16));
        s[kt] = __builtin_amdgcn_mfma_f32_16x16x32_f16(kf, qf[ks], s[kt], 0, 0, 0);
      }
    }

    // Online softmax over the 64 keys of this tile (per q column = l15).
    float tmax = -INFINITY;
#pragma unroll
    for (int kt = 0; kt < 4; kt++)
#pragma unroll
      for (int r = 0; r < 4; r++) tmax = fmaxf(tmax, s[kt][r]);
    tmax = fmaxf(tmax, __shfl_xor(tmax, 16));
    tmax = fmaxf(tmax, __shfl_xor(tmax, 32));
    float mnew = fmaxf(m_run, tmax);
    float alpha = __expf(m_run - mnew);

    float psum = 0.f;
    half4v pf[4];
#pragma unroll
    for (int kt = 0; kt < 4; kt++)
#pragma unroll
      for (int r = 0; r < 4; r++) {
        float p = __expf(s[kt][r] - mnew);
        psum += p;
        pf[kt][r] = (_Float16)p;
      }
    psum += __shfl_xor(psum, 16);
    psum += __shfl_xor(psum, 32);
    l_run = l_run * alpha + psum;
    m_run = mnew;
#pragma unroll
    for (int dt = 0; dt < 4; dt++) o[dt] *= alpha;

    // PV: o^T[d][q] += V^T x P, 4 d-tiles x 4 key-tiles of 16x16x16.
#pragma unroll
    for (int dt = 0; dt < 4; dt++) {
      int d = dt * 16 + l15;
#pragma unroll
      for (int kt = 0; kt < 4; kt++) {
        half4v vf = *(const half4v*)(
            (char*)Vs + d * 128 + (((kt * 2 + (quad >> 1)) ^ (d & 7)) * 16) +
            (quad & 1) * 8);
        o[dt] = __builtin_amdgcn_mfma_f32_16x16x16f16(vf, pf[kt], o[dt], 0, 0, 0);
      }
    }
    __syncthreads();
  }

  float inv = 1.0f / l_run;
#pragma unroll
  for (int dt = 0; dt < 4; dt++) {
    half4v yv;
#pragma unroll
    for (int r = 0; r < 4; r++) yv[r] = (_Float16)(o[dt][r] * inv);
    *(half4v*)(Yh + qoff + dt * 16 + quad * 4) = yv;  // row q, cols h*64+d..
  }
}

// ---------------------------------------------------------------------------
extern "C" void kernel_launch(void* const* d_in, const int* in_sizes, int n_in,
                              void* d_out, int out_size, void* d_ws, size_t ws_size,
                              hipStream_t stream) {
  const float* x  = (const float*)d_in[0];
  const float* Wq = (const float*)d_in[1];
  const float* bq = (const float*)d_in[2];
  const float* Wk = (const float*)d_in[3];
  const float* bk = (const float*)d_in[4];
  const float* Wv = (const float*)d_in[5];
  const float* bv = (const float*)d_in[6];
  const float* Wo = (const float*)d_in[7];
  const float* bo = (const float*)d_in[8];
  float* out = (float*)d_out;

  // Workspace carve-up (bytes). Each f16 plane M_*C_ = 8 MB.
  char* ws = (char*)d_ws;
  _Float16* xh   = (_Float16*)(ws);                        // 8 MB
  _Float16* Qh   = (_Float16*)(ws + (((size_t)8)  << 20)); // 8 MB
  _Float16* Kh   = (_Float16*)(ws + (((size_t)16) << 20)); // 8 MB
  _Float16* Vt   = (_Float16*)(ws + (((size_t)24) << 20)); // 8 MB  [b,h,d,t]
  _Float16* Yh   = (_Float16*)(ws + (((size_t)32) << 20)); // 8 MB
  _Float16* Wt3  = (_Float16*)(ws + (((size_t)40) << 20)); // 6 MB  [3072][1024]
  _Float16* Wot  = (_Float16*)(ws + (((size_t)46) << 20)); // 2 MB  [1024][1024]
  float*    b3   = (float*)   (ws + (((size_t)48) << 20)); // 12 KB

  cast_f16_kernel<<<(M_ * C_ / 4 + 255) / 256, 256, 0, stream>>>(x, xh, M_ * C_ / 4);

  dim3 tg(32, 32), tb(32, 8);
  transpose_cast_kernel<<<tg, tb, 0, stream>>>(Wq, Wt3);
  transpose_cast_kernel<<<tg, tb, 0, stream>>>(Wk, Wt3 + (size_t)1024 * 1024);
  transpose_cast_kernel<<<tg, tb, 0, stream>>>(Wv, Wt3 + (size_t)2048 * 1024);
  transpose_cast_kernel<<<tg, tb, 0, stream>>>(Wo, Wot);
  concat_bias_kernel<<<12, 256, 0, stream>>>(bq, bk, bv, b3);

  // Fused QKV projection: [4096,1024] @ [1024,3072] -> Q,K (f16) + V^T (f16).
  gemm_f16_kernel<128, 128, 0><<<dim3(24, 32), 256, 0, stream>>>(
      xh, Wt3, b3, Qh, Kh, Vt, nullptr);

  attn_f16_kernel<<<dim3(T_ / 64, H_, B_), 256, 0, stream>>>(Qh, Kh, Vt, Yh);

  // Output projection: Yh @ Wot^T + bo -> fp32 out.
  gemm_f16_kernel<64, 128, 1><<<dim3(8, 64), 256, 0, stream>>>(
      Yh, Wot, bo, nullptr, nullptr, nullptr, out);
}

// Round 5
// 223.067 us; speedup vs baseline: 7.7043x; 1.0600x over previous
//
#include <hip/hip_runtime.h>
#include <math.h>

#define B_ 2
#define T_ 2048
#define C_ 1024
#define H_ 16
#define HD_ 64
#define M_ (B_*T_)

typedef _Float16 half2v __attribute__((ext_vector_type(2)));
typedef _Float16 half4v __attribute__((ext_vector_type(4)));
typedef _Float16 half8v __attribute__((ext_vector_type(8)));
typedef float f32x4 __attribute__((ext_vector_type(4)));

#define GLD_LDS(gp, lp) \
  __builtin_amdgcn_global_load_lds( \
      (const __attribute__((address_space(1))) void*)(gp), \
      (__attribute__((address_space(3))) void*)(lp), 16, 0, 0)

// ---------------------------------------------------------------------------
// Elementwise fp32 -> f16 cast, float4-vectorized.
// ---------------------------------------------------------------------------
__global__ __launch_bounds__(256) void cast_f16_kernel(
    const float* __restrict__ src, _Float16* __restrict__ dst, int n4)
{
  int i = blockIdx.x * 256 + threadIdx.x;
  if (i < n4) {
    float4 v = ((const float4*)src)[i];
    half4v h; h[0] = (_Float16)v.x; h[1] = (_Float16)v.y;
    h[2] = (_Float16)v.z; h[3] = (_Float16)v.w;
    ((half4v*)dst)[i] = h;
  }
}

// ---------------------------------------------------------------------------
// All four W[K][N] fp32 -> Wt[n][k] f16 transposes in one launch (grid.z).
// ---------------------------------------------------------------------------
__global__ __launch_bounds__(256) void transpose_cast_all_kernel(
    const float* __restrict__ Wq, const float* __restrict__ Wk,
    const float* __restrict__ Wv, const float* __restrict__ Wo,
    _Float16* __restrict__ Wt3, _Float16* __restrict__ Wot)
{
  const float* W; _Float16* Wt;
  switch (blockIdx.z) {
    case 0:  W = Wq; Wt = Wt3; break;
    case 1:  W = Wk; Wt = Wt3 + (size_t)1024 * 1024; break;
    case 2:  W = Wv; Wt = Wt3 + (size_t)2048 * 1024; break;
    default: W = Wo; Wt = Wot; break;
  }
  __shared__ float tile[32][33];
  const int tx = threadIdx.x, ty = threadIdx.y;
  const int n0 = blockIdx.x * 32, k0 = blockIdx.y * 32;
#pragma unroll
  for (int r = 0; r < 4; r++) {
    int k = ty + r * 8;
    tile[k][tx] = W[(size_t)(k0 + k) * C_ + n0 + tx];
  }
  __syncthreads();
#pragma unroll
  for (int r = 0; r < 4; r++) {
    int n = ty + r * 8;
    Wt[(size_t)(n0 + n) * C_ + k0 + tx] = (_Float16)tile[tx][n];
  }
}

__global__ __launch_bounds__(256) void concat_bias_kernel(
    const float* __restrict__ bq, const float* __restrict__ bk,
    const float* __restrict__ bv, float* __restrict__ b3)
{
  int i = blockIdx.x * 256 + threadIdx.x;  // grid 12*256 = 3072
  const float* s = (i < 1024) ? bq : ((i < 2048) ? bk : bv);
  b3[i] = s[i & 1023];
}

// ---------------------------------------------------------------------------
// f16 MFMA GEMM: Out[M,N] = A[M,1024] @ Wt[N,1024]^T + bias.
// BK=32, 256 threads = 4 waves (2x2); wave tile (BM/2)x(BN/2).
// Staging via global_load_lds width=16 (m97 pattern): wave-uniform LDS base +
// lane*16; LDS layout is the raw [row][4x16B] global order (no swizzle).
// EPI 0: fused QKV epilogue (Q scaled by 0.125*log2e -> o0; K -> o1;
//        V transposed -> o2 as [b,h,d,t] f16).  EPI 1: fp32 out + bias (of).
// ---------------------------------------------------------------------------
template <int BM, int BN, int EPI>
__global__ __launch_bounds__(256) void gemm_f16_kernel(
    const _Float16* __restrict__ A, const _Float16* __restrict__ Bw,
    const float* __restrict__ bias,
    _Float16* __restrict__ o0, _Float16* __restrict__ o1,
    _Float16* __restrict__ o2, float* __restrict__ of)
{
  constexpr int FM = BM / 32, FN = BN / 32;
  __shared__ __align__(16) _Float16 As[BM * 32];
  __shared__ __align__(16) _Float16 Bs[BN * 32];
  const int t = threadIdx.x;
  const int w = t >> 6, lane = t & 63, l15 = lane & 15, quad = lane >> 4;
  const int wm = (w & 1) * (BM / 2), wn = (w >> 1) * (BN / 2);
  const int bm = blockIdx.y * BM, bn = blockIdx.x * BN;
  const int lrow = lane >> 2, lcol = (lane & 3) * 8;  // staging: 16 rows/call

  f32x4 acc[FM][FN];
#pragma unroll
  for (int i = 0; i < FM; i++)
#pragma unroll
    for (int j = 0; j < FN; j++) acc[i][j] = (f32x4){0.f, 0.f, 0.f, 0.f};

  for (int k0 = 0; k0 < 1024; k0 += 32) {
    // A tile: BM x 32 halves; each call stages 16 rows (64 lanes x 16B).
#pragma unroll
    for (int i = 0; i < BM / 64; i++) {
      int ca = w + 4 * i;          // 0 .. BM/16-1, uniform per wave
      int row = ca * 16 + lrow;
      GLD_LDS(A + (size_t)(bm + row) * 1024 + k0 + lcol, As + ca * 512);
    }
#pragma unroll
    for (int i = 0; i < BN / 64; i++) {
      int cb = w + 4 * i;
      int row = cb * 16 + lrow;
      GLD_LDS(Bw + (size_t)(bn + row) * 1024 + k0 + lcol, Bs + cb * 512);
    }
    __syncthreads();

    half8v af[FM], bf[FN];
#pragma unroll
    for (int mt = 0; mt < FM; mt++)
      af[mt] = *(const half8v*)(As + (wm + mt * 16 + l15) * 32 + quad * 8);
#pragma unroll
    for (int nt = 0; nt < FN; nt++)
      bf[nt] = *(const half8v*)(Bs + (wn + nt * 16 + l15) * 32 + quad * 8);
#pragma unroll
    for (int mt = 0; mt < FM; mt++)
#pragma unroll
      for (int nt = 0; nt < FN; nt++)
        acc[mt][nt] = __builtin_amdgcn_mfma_f32_16x16x32_f16(
            af[mt], bf[nt], acc[mt][nt], 0, 0, 0);
    __syncthreads();
  }

  // Epilogue. C/D layout: col = l15 (n), row = quad*4 + r (m).
#pragma unroll
  for (int mt = 0; mt < FM; mt++)
#pragma unroll
    for (int nt = 0; nt < FN; nt++) {
      int n = bn + wn + nt * 16 + l15;
      float bv = bias[n];
#pragma unroll
      for (int r = 0; r < 4; r++) {
        int m = bm + wm + mt * 16 + quad * 4 + r;
        float v = acc[mt][nt][r] + bv;
        if (EPI == 0) {
          if (bn < 1024) {
            // Q pre-scaled by 0.125 * log2(e) for base-2 softmax.
            o0[(size_t)m * 1024 + n] = (_Float16)(v * 0.180336884f);
          } else if (bn < 2048) {
            o1[(size_t)m * 1024 + (n - 1024)] = (_Float16)v;    // K
          } else {
            int dg = n - 2048;
            int hh = dg >> 6, hd = dg & 63;
            int bb = m >> 11, tt = m & 2047;
            o2[(((size_t)(bb * H_ + hh)) * 64 + hd) * 2048 + tt] = (_Float16)v;  // V^T
          }
        } else {
          of[(size_t)m * 1024 + n] = v;
        }
      }
    }
}

// ---------------------------------------------------------------------------
// MFMA flash attention (no mask, per reference). Grid (T/64, H, B), 256 thr.
// Wave w owns 16 query columns q = qt*64 + w*16 + l15.
// S^T = K·Q^T via 16x16x32_f16 (C-layout row=key, col=q); P lands exactly in
// the 16x16x16f16 B-operand layout -> PV with zero LDS round-trip.
// LDS rows padded to 136 B (68 halves): banks = 2*l15 + const per
// quarter/eighth-wave for every access pattern here -> conflict-free, no
// swizzle needed. Softmax in base-2 (Q carries 0.125*log2e).
// ---------------------------------------------------------------------------
__global__ __launch_bounds__(256) void attn_f16_kernel(
    const _Float16* __restrict__ Qh, const _Float16* __restrict__ Kh,
    const _Float16* __restrict__ Vt, _Float16* __restrict__ Yh)
{
  __shared__ __align__(16) _Float16 Ks[64 * 68];
  __shared__ __align__(16) _Float16 Vs[64 * 68];
  const int t = threadIdx.x;
  const int w = t >> 6, lane = t & 63, l15 = lane & 15, quad = lane >> 4;
  const int qt = blockIdx.x, h = blockIdx.y, b = blockIdx.z;
  const int qg = qt * 64 + w * 16 + l15;
  const size_t qoff = ((size_t)(b * T_ + qg)) * C_ + h * HD_;

  half8v qf[2];
  qf[0] = *(const half8v*)(Qh + qoff + quad * 8);
  qf[1] = *(const half8v*)(Qh + qoff + 32 + quad * 8);

  f32x4 o[4];
#pragma unroll
  for (int i = 0; i < 4; i++) o[i] = (f32x4){0.f, 0.f, 0.f, 0.f};
  float m_run = -INFINITY, l_run = 0.f;

  const size_t kbase = ((size_t)b * T_) * C_ + h * HD_;
  const size_t vbase = ((size_t)(b * H_ + h)) * HD_ * 2048;

  const int srow = t >> 3, scp = t & 7;  // staging: 8x16B chunks per row

  for (int kt0 = 0; kt0 < T_; kt0 += 64) {
    // Stage K (64 keys x 64 d) and V^T (64 d x 64 keys), rows padded 136 B.
#pragma unroll
    for (int i = 0; i < 2; i++) {
      int row = srow + i * 32;
      *(uint4*)((char*)Ks + row * 136 + scp * 16) =
          *(const uint4*)(Kh + kbase + (size_t)(kt0 + row) * C_ + scp * 8);
      *(uint4*)((char*)Vs + row * 136 + scp * 16) =
          *(const uint4*)(Vt + vbase + (size_t)row * 2048 + kt0 + scp * 8);
    }
    __syncthreads();

    // S^T tiles: 4 key-tiles x 2 d-steps of 16x16x32.
    f32x4 s[4];
#pragma unroll
    for (int kt = 0; kt < 4; kt++) {
      s[kt] = (f32x4){0.f, 0.f, 0.f, 0.f};
      int key = kt * 16 + l15;
#pragma unroll
      for (int ks = 0; ks < 2; ks++) {
        half8v kf = *(const half8v*)((char*)Ks + key * 136 + (ks * 4 + quad) * 16);
        s[kt] = __builtin_amdgcn_mfma_f32_16x16x32_f16(kf, qf[ks], s[kt], 0, 0, 0);
      }
    }

    // Online softmax (base-2) over the 64 keys of this tile, per q col = l15.
    float tmax = -INFINITY;
#pragma unroll
    for (int kt = 0; kt < 4; kt++)
#pragma unroll
      for (int r = 0; r < 4; r++) tmax = fmaxf(tmax, s[kt][r]);
    tmax = fmaxf(tmax, __shfl_xor(tmax, 16));
    tmax = fmaxf(tmax, __shfl_xor(tmax, 32));
    float mnew = fmaxf(m_run, tmax);
    float alpha = __builtin_amdgcn_exp2f(m_run - mnew);

    float psum = 0.f;
    half4v pf[4];
#pragma unroll
    for (int kt = 0; kt < 4; kt++) {
      float p0 = __builtin_amdgcn_exp2f(s[kt][0] - mnew);
      float p1 = __builtin_amdgcn_exp2f(s[kt][1] - mnew);
      float p2 = __builtin_amdgcn_exp2f(s[kt][2] - mnew);
      float p3 = __builtin_amdgcn_exp2f(s[kt][3] - mnew);
      psum += (p0 + p1) + (p2 + p3);
      half2v pk01 = __builtin_bit_cast(half2v, __builtin_amdgcn_cvt_pkrtz(p0, p1));
      half2v pk23 = __builtin_bit_cast(half2v, __builtin_amdgcn_cvt_pkrtz(p2, p3));
      pf[kt] = __builtin_shufflevector(pk01, pk23, 0, 1, 2, 3);
    }
    psum += __shfl_xor(psum, 16);
    psum += __shfl_xor(psum, 32);
    l_run = l_run * alpha + psum;
    m_run = mnew;
#pragma unroll
    for (int dt = 0; dt < 4; dt++) o[dt] *= alpha;

    // PV: o^T[d][q] += V^T x P, 4 d-tiles x 4 key-tiles of 16x16x16.
#pragma unroll
    for (int dt = 0; dt < 4; dt++) {
      int d = dt * 16 + l15;
#pragma unroll
      for (int kt = 0; kt < 4; kt++) {
        half4v vf = *(const half4v*)((char*)Vs + d * 136 + kt * 32 + quad * 8);
        o[dt] = __builtin_amdgcn_mfma_f32_16x16x16f16(vf, pf[kt], o[dt], 0, 0, 0);
      }
    }
    __syncthreads();
  }

  float inv = 1.0f / l_run;
#pragma unroll
  for (int dt = 0; dt < 4; dt++) {
    half4v yv;
#pragma unroll
    for (int r = 0; r < 4; r++) yv[r] = (_Float16)(o[dt][r] * inv);
    *(half4v*)(Yh + qoff + dt * 16 + quad * 4) = yv;  // row q, cols h*64+d..
  }
}

// ---------------------------------------------------------------------------
extern "C" void kernel_launch(void* const* d_in, const int* in_sizes, int n_in,
                              void* d_out, int out_size, void* d_ws, size_t ws_size,
                              hipStream_t stream) {
  const float* x  = (const float*)d_in[0];
  const float* Wq = (const float*)d_in[1];
  const float* bq = (const float*)d_in[2];
  const float* Wk = (const float*)d_in[3];
  const float* bk = (const float*)d_in[4];
  const float* Wv = (const float*)d_in[5];
  const float* bv = (const float*)d_in[6];
  const float* Wo = (const float*)d_in[7];
  const float* bo = (const float*)d_in[8];
  float* out = (float*)d_out;

  // Workspace carve-up (bytes). Each f16 plane M_*C_ = 8 MB.
  char* ws = (char*)d_ws;
  _Float16* xh   = (_Float16*)(ws);                        // 8 MB
  _Float16* Qh   = (_Float16*)(ws + (((size_t)8)  << 20)); // 8 MB
  _Float16* Kh   = (_Float16*)(ws + (((size_t)16) << 20)); // 8 MB
  _Float16* Vt   = (_Float16*)(ws + (((size_t)24) << 20)); // 8 MB  [b,h,d,t]
  _Float16* Yh   = (_Float16*)(ws + (((size_t)32) << 20)); // 8 MB
  _Float16* Wt3  = (_Float16*)(ws + (((size_t)40) << 20)); // 6 MB  [3072][1024]
  _Float16* Wot  = (_Float16*)(ws + (((size_t)46) << 20)); // 2 MB  [1024][1024]
  float*    b3   = (float*)   (ws + (((size_t)48) << 20)); // 12 KB

  cast_f16_kernel<<<(M_ * C_ / 4 + 255) / 256, 256, 0, stream>>>(x, xh, M_ * C_ / 4);
  transpose_cast_all_kernel<<<dim3(32, 32, 4), dim3(32, 8), 0, stream>>>(
      Wq, Wk, Wv, Wo, Wt3, Wot);
  concat_bias_kernel<<<12, 256, 0, stream>>>(bq, bk, bv, b3);

  // Fused QKV projection: [4096,1024] @ [1024,3072] -> Q,K (f16) + V^T (f16).
  gemm_f16_kernel<128, 128, 0><<<dim3(24, 32), 256, 0, stream>>>(
      xh, Wt3, b3, Qh, Kh, Vt, nullptr);

  attn_f16_kernel<<<dim3(T_ / 64, H_, B_), 256, 0, stream>>>(Qh, Kh, Vt, Yh);

  // Output projection: Yh @ Wot^T + bo -> fp32 out.
  gemm_f16_kernel<64, 128, 1><<<dim3(8, 64), 256, 0, stream>>>(
      Yh, Wot, bo, nullptr, nullptr, nullptr, out);
}